// Round 6
// baseline (83.077 us; speedup 1.0000x reference)
//
#include <hip/hip_runtime.h>

// Problem constants (from reference)
#define B        8192
#define N_IN     8
#define N_MFS    4
#define N_RULES  2048

#define THREADS  256
#define NB       16                   // batches per block
#define RSPLIT   4                    // rule groups: grid = (B/NB)*RSPLIT = 2048 blocks
#define RPB      (N_RULES / RSPLIT)   // 512 rules/block -> 2 rules/thread
#define LUT_S    18                   // batch-interleaved LUT stride (words)
#define XS_W     (N_IN * N_MFS)       // 32 floats per batch

typedef float vfloat2 __attribute__((ext_vector_type(2)));

// R12: single remaining unvaried structure — the gather itself.
//  Ledger: occupancy +, NT>regular +, store width null, write pattern
//  null, redundancy/instr-cut + (R11 79.9 = best). Main loop has issued
//  4 x broadcast ds_read_b32 per output (one batch per read) since R6:
//  4096 wave-reads/CU ~= 10us, the largest remaining instr-count term.
//  Change (one variable): LUT layout rest-major -> BATCH-INTERLEAVED,
//  slut2[rest*18 + bl]. Entry values for batches (bl,bl+1) are adjacent
//  words -> one ds_read_b64 serves TWO batches -> gather wave-instrs
//  halve (2048/CU, ~5us).
//  Stride 18 verified on paper:
//   - align: byte = woff*72 + bl*4, both 8B-multiples for even bl -> b64 legal.
//   - banks: 2-word windows; overlap needs 18*d === +-1 (mod 32) ->
//     impossible (18 even); d=16 aliases same-offset -> 2-way -> FREE (m136).
//  Unchanged (R11 proven): RSPLIT=4, NB=16, 2048 blocks = 32 waves/CU,
//  NT float2 stores (1/batch), conflict-free build, xs staging.
__global__ __launch_bounds__(THREADS, 8) void fire_kernel(
        const float* __restrict__ x,
        const int*   __restrict__ mf,
        float* __restrict__ out)
{
    __shared__ float xs[NB * XS_W];                       // 2 KB
    __shared__ __align__(16) float slut2[100 * LUT_S + NB]; // 7.3 KB

    const int tid = threadIdx.x;
    const int rg  = blockIdx.x;          // rule group 0..3
    const int bg  = blockIdx.y;          // batch group 0..511
    const int b0  = bg * NB;
    const int r0  = rg * RPB + tid * 2;  // this thread's 2 consecutive rules

    // ---- Stage this block's x slice: 512 floats = 128 x float4, coalesced.
    if (tid < (NB * XS_W) / 4) {
        ((float4*)xs)[tid] = ((const float4*)(x + (size_t)b0 * XS_W))[tid];
    }

    // ---- Pack this thread's 2 rules into 8 register word offsets.
    int woff[2][4];
#pragma unroll
    for (int j = 0; j < 2; ++j) {
        const int4* mr = (const int4*)(mf + (size_t)(r0 + j) * N_IN);
        const int4 lo = mr[0];
        const int4 hi = mr[1];
        const int idx[8] = {lo.x, lo.y, lo.z, lo.w, hi.x, hi.y, hi.z, hi.w};
#pragma unroll
        for (int p = 0; p < 4; ++p) {
            const int a = idx[2*p]   < 0 ? 4 : idx[2*p];
            const int b = idx[2*p+1] < 0 ? 4 : idx[2*p+1];
            woff[j][p] = p * 25 + a * 5 + b;     // 0..99
        }
    }
    __syncthreads();   // xs ready

    // ---- Build interleaved LUTs: slut2[rest*18 + bl] = va*vb.
    //      e = rest*16 + bl, 1600 entries, 256 threads -> ~6 iters.
    for (int e = tid; e < 100 * NB; e += THREADS) {
        const int rest = e >> 4;
        const int bl   = e & 15;
        const int p    = rest / 25;
        const int c    = rest - p * 25;
        const int a    = c / 5;
        const int bb   = c - a * 5;
        const float* xb = xs + bl * XS_W;
        const float va = (a  < 4) ? xb[(2*p)   * N_MFS + a ] : 1.0f;
        const float vb = (bb < 4) ? xb[(2*p+1) * N_MFS + bb] : 1.0f;
        slut2[rest * LUT_S + bl] = va * vb;
    }
    __syncthreads();   // slut2 ready

    // ---- Main loop over batch PAIRS: 8 x ds_read_b64 (2 rules x 4 p,
    //      each read = 2 batches) + 12 muls + 2 NT float2 stores.
    float* o = out + (size_t)b0 * N_RULES + rg * RPB + tid * 2;
#pragma unroll 2
    for (int q = 0; q < NB / 2; ++q) {
        const int bl = q * 2;
        const vfloat2 a0 = *(const vfloat2*)&slut2[woff[0][0] * LUT_S + bl];
        const vfloat2 a1 = *(const vfloat2*)&slut2[woff[0][1] * LUT_S + bl];
        const vfloat2 a2 = *(const vfloat2*)&slut2[woff[0][2] * LUT_S + bl];
        const vfloat2 a3 = *(const vfloat2*)&slut2[woff[0][3] * LUT_S + bl];
        const vfloat2 c0 = *(const vfloat2*)&slut2[woff[1][0] * LUT_S + bl];
        const vfloat2 c1 = *(const vfloat2*)&slut2[woff[1][1] * LUT_S + bl];
        const vfloat2 c2 = *(const vfloat2*)&slut2[woff[1][2] * LUT_S + bl];
        const vfloat2 c3 = *(const vfloat2*)&slut2[woff[1][3] * LUT_S + bl];

        vfloat2 s0, s1;                 // s0 = batch bl, s1 = batch bl+1
        s0.x = (a0.x * a1.x) * (a2.x * a3.x);   // rule 0, batch bl
        s0.y = (c0.x * c1.x) * (c2.x * c3.x);   // rule 1, batch bl
        s1.x = (a0.y * a1.y) * (a2.y * a3.y);   // rule 0, batch bl+1
        s1.y = (c0.y * c1.y) * (c2.y * c3.y);   // rule 1, batch bl+1

        __builtin_nontemporal_store(s0, (vfloat2*)(o + (size_t)bl * N_RULES));
        __builtin_nontemporal_store(s1, (vfloat2*)(o + (size_t)(bl + 1) * N_RULES));
    }
}

extern "C" void kernel_launch(void* const* d_in, const int* in_sizes, int n_in,
                              void* d_out, int out_size, void* d_ws, size_t ws_size,
                              hipStream_t stream) {
    const float* x  = (const float*)d_in[0];   // (B, N_IN, N_MFS) fp32
    const int*   mf = (const int*)d_in[1];     // (N_RULES, N_IN) int32
    float* out = (float*)d_out;                // (B, N_RULES) fp32
    (void)d_ws; (void)ws_size;

    dim3 grid(RSPLIT, B / NB);
    fire_kernel<<<grid, THREADS, 0, stream>>>(x, mf, out);
}